// Round 2
// baseline (98.749 us; speedup 1.0000x reference)
//
#include <hip/hip_runtime.h>
#include <hip/hip_bf16.h>

#define LDIM 4096
#define BDIM 4
#define DDIM 64
#define CSTRIDE 132   // 128 + 4 pad: fragment writes 2-way conflict (free), 16B-aligned rows

typedef __attribute__((ext_vector_type(4))) float f32x4;
typedef __attribute__((ext_vector_type(8))) __bf16 bf16x8;

// Stage 1: Q[b,m,d] = sum_e K[d,e] * t1[m,b,e]  (bf16 out),
//          A[b,m,d] = bf16(t0[m,b,d])           (repack for per-b GEMM)
__global__ __launch_bounds__(256) void prep_kernel(
    const float* __restrict__ t0,
    const float* __restrict__ t1,
    const float* __restrict__ kmat,
    __hip_bfloat16* __restrict__ Abf,
    __hip_bfloat16* __restrict__ Qbf)
{
    __shared__ float kT[DDIM][DDIM];   // kT[e][d] = kmat[d][e] (transposed: conflict-free reads)
    __shared__ float rows[4][DDIM];
    const int tid = threadIdx.x;
    for (int i = tid; i < DDIM * DDIM; i += 256) {
        const int d = i >> 6, e = i & 63;
        kT[e][d] = kmat[i];            // kmat[d*64 + e]
    }
    const int sub = tid >> 6;          // which of 4 rows this block handles
    const int d   = tid & 63;
    const int r   = blockIdx.x * 4 + sub;   // r = m*B + b (flat row of [L,B] majors)
    rows[sub][d] = t1[(size_t)r * DDIM + d];
    __syncthreads();

    float acc = 0.f;
#pragma unroll
    for (int e = 0; e < DDIM; ++e)
        acc = fmaf(kT[e][d], rows[sub][e], acc);

    const int m = r >> 2;   // r / B
    const int b = r & 3;    // r % B
    const size_t o = ((size_t)(b * LDIM) + m) * DDIM + d;
    Qbf[o] = __float2bfloat16(acc);
    Abf[o] = __float2bfloat16(t0[(size_t)r * DDIM + d]);
}

// Stage 2: per-b GEMM, C[b][l][m] = sum_d A[b][l][d] * Q[b][m][d] + bias.
// 128x128 tile per block, 4 waves of 64x64, K=64 in registers (no staging LDS).
// Epilogue: stage tile in LDS, write out fully coalesced float4 (512B segments).
__global__ __launch_bounds__(256) void gemm_kernel(
    const __hip_bfloat16* __restrict__ Abf,
    const __hip_bfloat16* __restrict__ Qbf,
    const float* __restrict__ bias,
    float* __restrict__ out)
{
    __shared__ float ctile[128 * CSTRIDE];   // 67.6 KB -> 2 blocks/CU

    const int bid = blockIdx.x;
    const int b   = bid >> 10;       // / (32*32)
    const int t   = bid & 1023;
    const int tr  = t >> 5;          // tile row (of 32)
    const int tc  = t & 31;          // tile col
    const int tid  = threadIdx.x;
    const int w    = tid >> 6;
    const int lane = tid & 63;
    const int wr = w >> 1, wc = w & 1;      // 2x2 waves -> 64x64 each
    const int lr  = lane & 15;
    const int lhi = lane >> 4;

    const __hip_bfloat16* A  = Abf + (size_t)b * LDIM * DDIM;
    const __hip_bfloat16* Bq = Qbf + (size_t)b * LDIM * DDIM;

    // A fragment: lane holds A[row = base + (lane&15)][k = (lane>>4)*8 + j]
    bf16x8 af[4][2], bf[4][2];
#pragma unroll
    for (int mi = 0; mi < 4; ++mi) {
        const int row = tr * 128 + wr * 64 + mi * 16 + lr;
#pragma unroll
        for (int ks = 0; ks < 2; ++ks)
            af[mi][ks] = *(const bf16x8*)(A + (size_t)row * DDIM + ks * 32 + lhi * 8);
    }
#pragma unroll
    for (int ni = 0; ni < 4; ++ni) {
        const int row = tc * 128 + wc * 64 + ni * 16 + lr;
#pragma unroll
        for (int ks = 0; ks < 2; ++ks)
            bf[ni][ks] = *(const bf16x8*)(Bq + (size_t)row * DDIM + ks * 32 + lhi * 8);
    }

    f32x4 acc[4][4] = {};
#pragma unroll
    for (int ks = 0; ks < 2; ++ks)
#pragma unroll
        for (int mi = 0; mi < 4; ++mi)
#pragma unroll
            for (int ni = 0; ni < 4; ++ni)
                acc[mi][ni] = __builtin_amdgcn_mfma_f32_16x16x32_bf16(
                    af[mi][ks], bf[ni][ks], acc[mi][ni], 0, 0, 0);

    // Stage to LDS: acc[mi][ni][j] -> row = wr*64+mi*16+lhi*4+j, col = wc*64+ni*16+lr
#pragma unroll
    for (int mi = 0; mi < 4; ++mi) {
        const int rbase = wr * 64 + mi * 16 + lhi * 4;
#pragma unroll
        for (int ni = 0; ni < 4; ++ni) {
            const int col = wc * 64 + ni * 16 + lr;
#pragma unroll
            for (int j = 0; j < 4; ++j)
                ctile[(rbase + j) * CSTRIDE + col] = acc[mi][ni][j];
        }
    }
    __syncthreads();

    // Coalesced writeout: 256 threads x float4 = 8 rows/iter, 16 iters.
    const float bs = bias[0];
    float* outb = out + (size_t)b * LDIM * LDIM
                      + (size_t)(tr * 128) * LDIM + tc * 128;
    const int rof = tid >> 5;           // 0..7
    const int cof = (tid & 31) * 4;     // 0..124
#pragma unroll
    for (int it = 0; it < 16; ++it) {
        const int r = it * 8 + rof;
        f32x4 v = *(const f32x4*)&ctile[r * CSTRIDE + cof];
        v[0] += bs; v[1] += bs; v[2] += bs; v[3] += bs;
        *(f32x4*)&outb[(size_t)r * LDIM + cof] = v;
    }
}

extern "C" void kernel_launch(void* const* d_in, const int* in_sizes, int n_in,
                              void* d_out, int out_size, void* d_ws, size_t ws_size,
                              hipStream_t stream) {
    const float* t0   = (const float*)d_in[0];
    const float* t1   = (const float*)d_in[1];
    const float* km   = (const float*)d_in[2];
    const float* bias = (const float*)d_in[3];
    float* out = (float*)d_out;

    __hip_bfloat16* Abf = (__hip_bfloat16*)d_ws;                 // [B][L][D] bf16 = 2 MB
    __hip_bfloat16* Qbf = Abf + (size_t)BDIM * LDIM * DDIM;      // [B][L][D] bf16 = 2 MB

    prep_kernel<<<LDIM * BDIM / 4, 256, 0, stream>>>(t0, t1, km, Abf, Qbf);
    gemm_kernel<<<BDIM * 32 * 32, 256, 0, stream>>>(Abf, Qbf, bias, out);
}

// Round 3
// 55.086 us; speedup vs baseline: 1.7926x; 1.7926x over previous
//
#include <hip/hip_runtime.h>
#include <hip/hip_bf16.h>

#define LDIM 4096
#define BDIM 4
#define DDIM 64

typedef __attribute__((ext_vector_type(4))) float f32x4;
typedef __attribute__((ext_vector_type(8))) __bf16 bf16x8;

__device__ __forceinline__ bf16x8 cvt8(f32x4 a, f32x4 b) {
    bf16x8 r;
    r[0] = (__bf16)a[0]; r[1] = (__bf16)a[1]; r[2] = (__bf16)a[2]; r[3] = (__bf16)a[3];
    r[4] = (__bf16)b[0]; r[5] = (__bf16)b[1]; r[6] = (__bf16)b[2]; r[7] = (__bf16)b[3];
    return r;
}

__device__ __forceinline__ void gload_lds16(const void* g, void* l) {
    __builtin_amdgcn_global_load_lds(
        (const __attribute__((address_space(1))) void*)g,
        (__attribute__((address_space(3))) void*)l, 16, 0, 0);
}

// Stage 1 (MFMA-based): Q[b,m,d] = sum_e t1[m,b,e] * K[d,e] (bf16 out),
//                       A[b,m,d] = bf16(t0[m,b,d]).
// Flat row index r = m*B + b over [0,16384). 256 blocks x 256 threads,
// each block: 64 rows (4 waves x 16-row MFMA tile) + 64 rows of t0 convert.
__global__ __launch_bounds__(256) void prep_kernel(
    const float* __restrict__ t0,
    const float* __restrict__ t1,
    const float* __restrict__ kmat,
    __hip_bfloat16* __restrict__ Abf,
    __hip_bfloat16* __restrict__ Qbf)
{
    const int tid  = threadIdx.x;
    const int w    = tid >> 6;
    const int lane = tid & 63;
    const int lr   = lane & 15;
    const int lhi  = lane >> 4;
    const int rbase = blockIdx.x * 64 + w * 16;

    // Q via mfma_f32_16x16x32_bf16: A-op = t1 rows, B-op = kmat rows.
    f32x4 acc[4] = {{0.f,0.f,0.f,0.f},{0.f,0.f,0.f,0.f},{0.f,0.f,0.f,0.f},{0.f,0.f,0.f,0.f}};
#pragma unroll
    for (int ks = 0; ks < 2; ++ks) {
        const float* ap = t1 + (size_t)(rbase + lr) * DDIM + ks * 32 + lhi * 8;
        bf16x8 af = cvt8(*(const f32x4*)ap, *(const f32x4*)(ap + 4));
#pragma unroll
        for (int nt = 0; nt < 4; ++nt) {
            const float* bp = kmat + (size_t)(nt * 16 + lr) * DDIM + ks * 32 + lhi * 8;
            bf16x8 bq = cvt8(*(const f32x4*)bp, *(const f32x4*)(bp + 4));
            acc[nt] = __builtin_amdgcn_mfma_f32_16x16x32_bf16(af, bq, acc[nt], 0, 0, 0);
        }
    }
    // C layout: col(d_local)=lane&15, row(r_local)=(lane>>4)*4+j
#pragma unroll
    for (int nt = 0; nt < 4; ++nt) {
#pragma unroll
        for (int j = 0; j < 4; ++j) {
            const int r = rbase + lhi * 4 + j;
            const int m = r >> 2, b = r & 3;
            Qbf[((size_t)(b * LDIM) + m) * DDIM + nt * 16 + lr] =
                __float2bfloat16(acc[nt][j]);
        }
    }

    // t0 pass-through convert: this block's 64 rows = 4096 elems, 16/thread.
    {
        const int r2 = blockIdx.x * 64 + (tid >> 2);
        const int d0 = (tid & 3) * 16;
        const float* src = t0 + (size_t)r2 * DDIM + d0;
        f32x4 v0 = *(const f32x4*)(src + 0);
        f32x4 v1 = *(const f32x4*)(src + 4);
        f32x4 v2 = *(const f32x4*)(src + 8);
        f32x4 v3 = *(const f32x4*)(src + 12);
        const int m2 = r2 >> 2, b2 = r2 & 3;
        __hip_bfloat16* dst = Abf + ((size_t)(b2 * LDIM) + m2) * DDIM + d0;
        *(bf16x8*)dst       = cvt8(v0, v1);
        *(bf16x8*)(dst + 8) = cvt8(v2, v3);
    }
}

// Stage 2: per-b GEMM, C[b][l][m] = sum_d A[b][l][d] * Q[b][m][d] + bias.
// 256x256 tile per block, 8 waves (2x4), wave tile 128x64, K=64 (2 k-steps).
// A/B staged in LDS via global_load_lds w/ pre-swizzled source (XOR chunk^row&7);
// fragment ds_read_b128 applies the same XOR -> 2-way bank conflicts only.
__global__ __launch_bounds__(512, 2) void gemm_kernel(
    const __hip_bfloat16* __restrict__ Abf,
    const __hip_bfloat16* __restrict__ Qbf,
    const float* __restrict__ bias,
    float* __restrict__ out)
{
    __shared__ char smem[65536];   // A tile [0,32K), B tile [32K,64K)

    // chunked XCD swizzle: 1024 blocks, 8 XCDs, 128-contiguous per XCD
    const int bid0 = blockIdx.x;
    const int swz  = (bid0 & 7) * 128 + (bid0 >> 3);
    const int b    = swz >> 8;          // 256 tiles per b
    const int t    = swz & 255;
    const int tr   = t >> 4;
    const int tc   = t & 15;

    const int tid  = threadIdx.x;
    const int w    = tid >> 6;
    const int lane = tid & 63;
    const int wr   = w >> 2, wc = w & 3;    // 2x4 waves
    const int lr   = lane & 15;
    const int lhi  = lane >> 4;

    const char* Apan = (const char*)(Abf + ((size_t)b * LDIM + tr * 256) * DDIM);
    const char* Bpan = (const char*)(Qbf + ((size_t)b * LDIM + tc * 256) * DDIM);

    // Stage: 32 KB per tile = 32 chunks of 1KB (8 rows each); wave w does
    // chunks {i*8+w}. Source pre-swizzled so linear LDS holds XOR'd layout.
#pragma unroll
    for (int i = 0; i < 4; ++i) {
        const int ci  = i * 8 + w;
        const int row = ci * 8 + (lane >> 3);                 // 0..255
        const int so  = row * 128 + (((lane & 7) ^ (row & 7)) << 4);
        gload_lds16(Apan + so, smem + ci * 1024);
        gload_lds16(Bpan + so, smem + 32768 + ci * 1024);
    }
    __syncthreads();

    const char* As = smem;
    const char* Bs = smem + 32768;

    f32x4 acc[8][4] = {};
#pragma unroll
    for (int ks = 0; ks < 2; ++ks) {
        const int kx = ks * 4 + lhi;                          // 16B chunk in row
        bf16x8 af[8], bq[4];
#pragma unroll
        for (int mi = 0; mi < 8; ++mi) {
            const int row = wr * 128 + mi * 16 + lr;          // row&7 == lr&7
            af[mi] = *(const bf16x8*)(As + row * 128 + ((kx ^ (lr & 7)) << 4));
        }
#pragma unroll
        for (int ni = 0; ni < 4; ++ni) {
            const int row = wc * 64 + ni * 16 + lr;
            bq[ni] = *(const bf16x8*)(Bs + row * 128 + ((kx ^ (lr & 7)) << 4));
        }
#pragma unroll
        for (int mi = 0; mi < 8; ++mi)
#pragma unroll
            for (int ni = 0; ni < 4; ++ni)
                acc[mi][ni] = __builtin_amdgcn_mfma_f32_16x16x32_bf16(
                    af[mi], bq[ni], acc[mi][ni], 0, 0, 0);
    }

    // Epilogue: direct stores (round 2 showed store pattern is not the limiter)
    const float bs = bias[0];
    float* outp = out + (size_t)b * LDIM * LDIM;
    const int rowb = tr * 256 + wr * 128;
    const int colb = tc * 256 + wc * 64;
#pragma unroll
    for (int mi = 0; mi < 8; ++mi) {
#pragma unroll
        for (int ni = 0; ni < 4; ++ni) {
            const int col = colb + ni * 16 + lr;
#pragma unroll
            for (int j = 0; j < 4; ++j) {
                const int row = rowb + mi * 16 + lhi * 4 + j;
                outp[(size_t)row * LDIM + col] = acc[mi][ni][j] + bs;
            }
        }
    }
}

extern "C" void kernel_launch(void* const* d_in, const int* in_sizes, int n_in,
                              void* d_out, int out_size, void* d_ws, size_t ws_size,
                              hipStream_t stream) {
    const float* t0   = (const float*)d_in[0];
    const float* t1   = (const float*)d_in[1];
    const float* km   = (const float*)d_in[2];
    const float* bias = (const float*)d_in[3];
    float* out = (float*)d_out;

    __hip_bfloat16* Abf = (__hip_bfloat16*)d_ws;                 // [B][L][D] bf16 = 2 MB
    __hip_bfloat16* Qbf = Abf + (size_t)BDIM * LDIM * DDIM;      // [B][L][D] bf16 = 2 MB

    prep_kernel<<<256, 256, 0, stream>>>(t0, t1, km, Abf, Qbf);
    gemm_kernel<<<BDIM * 16 * 16, 512, 0, stream>>>(Abf, Qbf, bias, out);
}

// Round 4
// 54.052 us; speedup vs baseline: 1.8269x; 1.0191x over previous
//
#include <hip/hip_runtime.h>
#include <hip/hip_bf16.h>

#define LDIM 4096
#define BDIM 4
#define DDIM 64

typedef __attribute__((ext_vector_type(4))) float f32x4;
typedef __attribute__((ext_vector_type(8))) __bf16 bf16x8;

__device__ __forceinline__ bf16x8 cvt8(f32x4 a, f32x4 b) {
    bf16x8 r;
    r[0] = (__bf16)a[0]; r[1] = (__bf16)a[1]; r[2] = (__bf16)a[2]; r[3] = (__bf16)a[3];
    r[4] = (__bf16)b[0]; r[5] = (__bf16)b[1]; r[6] = (__bf16)b[2]; r[7] = (__bf16)b[3];
    return r;
}

__device__ __forceinline__ void gload_lds16(const void* g, void* l) {
    __builtin_amdgcn_global_load_lds(
        (const __attribute__((address_space(1))) void*)g,
        (__attribute__((address_space(3))) void*)l, 16, 0, 0);
}

// Stage 1 (MFMA-based): Q[b,m,d] = sum_e t1[m,b,e] * K[d,e] (bf16 out),
//                       A[b,m,d] = bf16(t0[m,b,d]).
__global__ __launch_bounds__(256) void prep_kernel(
    const float* __restrict__ t0,
    const float* __restrict__ t1,
    const float* __restrict__ kmat,
    __hip_bfloat16* __restrict__ Abf,
    __hip_bfloat16* __restrict__ Qbf)
{
    const int tid  = threadIdx.x;
    const int w    = tid >> 6;
    const int lane = tid & 63;
    const int lr   = lane & 15;
    const int lhi  = lane >> 4;
    const int rbase = blockIdx.x * 64 + w * 16;

    f32x4 acc[4] = {{0.f,0.f,0.f,0.f},{0.f,0.f,0.f,0.f},{0.f,0.f,0.f,0.f},{0.f,0.f,0.f,0.f}};
#pragma unroll
    for (int ks = 0; ks < 2; ++ks) {
        const float* ap = t1 + (size_t)(rbase + lr) * DDIM + ks * 32 + lhi * 8;
        bf16x8 af = cvt8(*(const f32x4*)ap, *(const f32x4*)(ap + 4));
#pragma unroll
        for (int nt = 0; nt < 4; ++nt) {
            const float* bp = kmat + (size_t)(nt * 16 + lr) * DDIM + ks * 32 + lhi * 8;
            bf16x8 bq = cvt8(*(const f32x4*)bp, *(const f32x4*)(bp + 4));
            acc[nt] = __builtin_amdgcn_mfma_f32_16x16x32_bf16(af, bq, acc[nt], 0, 0, 0);
        }
    }
#pragma unroll
    for (int nt = 0; nt < 4; ++nt) {
#pragma unroll
        for (int j = 0; j < 4; ++j) {
            const int r = rbase + lhi * 4 + j;
            const int m = r >> 2, b = r & 3;
            Qbf[((size_t)(b * LDIM) + m) * DDIM + nt * 16 + lr] =
                __float2bfloat16(acc[nt][j]);
        }
    }

    {
        const int r2 = blockIdx.x * 64 + (tid >> 2);
        const int d0 = (tid & 3) * 16;
        const float* src = t0 + (size_t)r2 * DDIM + d0;
        f32x4 v0 = *(const f32x4*)(src + 0);
        f32x4 v1 = *(const f32x4*)(src + 4);
        f32x4 v2 = *(const f32x4*)(src + 8);
        f32x4 v3 = *(const f32x4*)(src + 12);
        const int m2 = r2 >> 2, b2 = r2 & 3;
        __hip_bfloat16* dst = Abf + ((size_t)(b2 * LDIM) + m2) * DDIM + d0;
        *(bf16x8*)dst       = cvt8(v0, v1);
        *(bf16x8*)(dst + 8) = cvt8(v2, v3);
    }
}

// Stage 2: per-b GEMM, C[b][l][m] = sum_d A[b][l][d] * Q[b][m][d] + bias.
// 128x256 tile per block, 8 waves (2x4) of 64x64 each -> acc=64 VGPR,
// __launch_bounds__(512,4) caps VGPR at 128 -> 2 blocks/CU: block N+1's
// stage/MFMA overlaps block N's store drain.
__global__ __launch_bounds__(512, 4) void gemm_kernel(
    const __hip_bfloat16* __restrict__ Abf,
    const __hip_bfloat16* __restrict__ Qbf,
    const float* __restrict__ bias,
    float* __restrict__ out)
{
    __shared__ char smem[49152];   // A tile [0,16K), B tile [16K,48K)

    // chunked XCD swizzle: 2048 blocks, 8 XCDs, 256-contiguous per XCD
    const int bid0 = blockIdx.x;
    const int swz  = (bid0 & 7) * 256 + (bid0 >> 3);
    const int b    = swz >> 9;          // 512 tiles per b (32 tr x 16 tc)
    const int t    = swz & 511;
    const int tr   = t >> 4;
    const int tc   = t & 15;

    const int tid  = threadIdx.x;
    const int w    = tid >> 6;
    const int lane = tid & 63;
    const int wr   = w >> 2, wc = w & 3;    // 2x4 waves, 64x64 each
    const int lr   = lane & 15;
    const int lhi  = lane >> 4;

    const char* Apan = (const char*)(Abf + ((size_t)b * LDIM + tr * 128) * DDIM);
    const char* Bpan = (const char*)(Qbf + ((size_t)b * LDIM + tc * 256) * DDIM);

    // Stage A: 16 KB = 16 chunks of 1KB (8 rows); wave w does {w, w+8}.
    // Source pre-swizzled (chunk^row&7) so linear LDS holds XOR'd layout.
#pragma unroll
    for (int i = 0; i < 2; ++i) {
        const int ci  = i * 8 + w;
        const int row = ci * 8 + (lane >> 3);
        const int so  = row * 128 + (((lane & 7) ^ (row & 7)) << 4);
        gload_lds16(Apan + so, smem + ci * 1024);
    }
    // Stage B: 32 KB = 32 chunks; wave w does {i*8+w}.
#pragma unroll
    for (int i = 0; i < 4; ++i) {
        const int ci  = i * 8 + w;
        const int row = ci * 8 + (lane >> 3);
        const int so  = row * 128 + (((lane & 7) ^ (row & 7)) << 4);
        gload_lds16(Bpan + so, smem + 16384 + ci * 1024);
    }
    __syncthreads();

    const char* As = smem;
    const char* Bs = smem + 16384;

    f32x4 acc[4][4] = {};
#pragma unroll
    for (int ks = 0; ks < 2; ++ks) {
        const int kx = ks * 4 + lhi;
        bf16x8 af[4], bq[4];
#pragma unroll
        for (int mi = 0; mi < 4; ++mi) {
            const int row = wr * 64 + mi * 16 + lr;
            af[mi] = *(const bf16x8*)(As + row * 128 + ((kx ^ (lr & 7)) << 4));
        }
#pragma unroll
        for (int ni = 0; ni < 4; ++ni) {
            const int row = wc * 64 + ni * 16 + lr;
            bq[ni] = *(const bf16x8*)(Bs + row * 128 + ((kx ^ (lr & 7)) << 4));
        }
#pragma unroll
        for (int mi = 0; mi < 4; ++mi)
#pragma unroll
            for (int ni = 0; ni < 4; ++ni)
                acc[mi][ni] = __builtin_amdgcn_mfma_f32_16x16x32_bf16(
                    af[mi], bq[ni], acc[mi][ni], 0, 0, 0);
    }

    const float bs = bias[0];
    float* outp = out + (size_t)b * LDIM * LDIM;
    const int rowb = tr * 128 + wr * 64;
    const int colb = tc * 256 + wc * 64;
#pragma unroll
    for (int mi = 0; mi < 4; ++mi) {
#pragma unroll
        for (int ni = 0; ni < 4; ++ni) {
            const int col = colb + ni * 16 + lr;
#pragma unroll
            for (int j = 0; j < 4; ++j) {
                const int row = rowb + mi * 16 + lhi * 4 + j;
                outp[(size_t)row * LDIM + col] = acc[mi][ni][j] + bs;
            }
        }
    }
}

extern "C" void kernel_launch(void* const* d_in, const int* in_sizes, int n_in,
                              void* d_out, int out_size, void* d_ws, size_t ws_size,
                              hipStream_t stream) {
    const float* t0   = (const float*)d_in[0];
    const float* t1   = (const float*)d_in[1];
    const float* km   = (const float*)d_in[2];
    const float* bias = (const float*)d_in[3];
    float* out = (float*)d_out;

    __hip_bfloat16* Abf = (__hip_bfloat16*)d_ws;                 // [B][L][D] bf16 = 2 MB
    __hip_bfloat16* Qbf = Abf + (size_t)BDIM * LDIM * DDIM;      // [B][L][D] bf16 = 2 MB

    prep_kernel<<<256, 256, 0, stream>>>(t0, t1, km, Abf, Qbf);
    gemm_kernel<<<2048, 512, 0, stream>>>(Abf, Qbf, bias, out);
}